// Round 5
// baseline (342.150 us; speedup 1.0000x reference)
//
#include <hip/hip_runtime.h>
#include <limits.h>

// RWKV integer WKV recurrence on MI355X (gfx950).
// B*C = 16384 independent sequences -> 256 wave64, 1 per SIMD (256 of 1024).
// T-recurrence is non-associative (RNE rounding + saturating clip) -> no T-split.
// One wave saturates its SIMD's VALU pipe (wave64 = 2cy/issue) if never stalled;
// runtime ~= (2*VALU + mem-issues)/step * 1024 steps. Slot-minimization:
//   - e-values: med3-clamped LDS lookups; clamp auto-yields lut[1024]=exp(0) on
//     the trivial side of each max(). Both deltas are (pp-kk) +/- loop-invariant
//     constants -> 8 VALU + 4 med3 + 4 ds_read per step in phase A.
//   - RNE >>14: (a*e + 8192) via v_mad_[iu]64, alignbit shift, and+cmp+sub
//     tie-to-even fix ((x2 & 32767) == 16384  <=>  r == 8192 && q even).
//   - int32 clip via saturating add (RNE result proven to fit int32).
//   - uniform SGPR row bases + loop-invariant VGPR lane offset for k/v/y.
//   - TB=16 phase-split blocks: 64 ds_reads issue a phase ahead of use; k/v
//     register-prefetched one full block (~3000 cy) ahead; 8 KB/wave in flight
//     covers ~900 cy HBM latency at the ~2.3 TB/s this kernel streams.

#define TPB 64
#define CC  2048
#define TT  1024
#define BBATCH 8
#define TB  16
#define NTB (TT / TB)      // 64
#define NTB2 (NTB / 2)     // 32

static __device__ __forceinline__ int sat_add(int a, int b) {
#if __has_builtin(__builtin_elementwise_add_sat)
    return __builtin_elementwise_add_sat(a, b);   // v_add_i32 ... clamp
#else
    long long s = (long long)a + (long long)b;
    return s < (long long)INT_MIN ? INT_MIN
         : (s > (long long)INT_MAX ? INT_MAX : (int)s);
#endif
}

// RNE((a*e) / 2^14), signed. Floor-form RNE == reference's sign-magnitude RNE
// (RNE is odd-symmetric). Result fits int32 for |a| <= 2^31, 0 <= e <= 2^14
// (extreme a=INT_MIN,e=2^14 -> exactly INT_MIN; a=INT_MAX,e=2^14 -> INT_MAX).
static __device__ __forceinline__ int rne14_s(int a, int e) {
    long long x2 = (long long)a * e + 8192;            // v_mad_i64_i32
    int q1 = (int)((unsigned long long)x2 >> 14);      // bits[45:14]: v_alignbit
    int tie = (((unsigned)x2 & 32767u) == 16384u);     // r==8192 && q even
    return q1 - tie;
}

static __device__ __forceinline__ unsigned rne14_u(unsigned a, unsigned e) {
    unsigned long long x2 = (unsigned long long)a * e + 8192u;  // v_mad_u64_u32
    unsigned q1 = (unsigned)(x2 >> 14);
    unsigned tie = (((unsigned)x2 & 32767u) == 16384u);
    return q1 - tie;
}

__launch_bounds__(TPB, 1)
__global__ void wkv_int_kernel(const int* __restrict__ w_i, const int* __restrict__ u_i,
                               const int* __restrict__ k_i, const int* __restrict__ v_i,
                               const int* __restrict__ lut, int* __restrict__ y)
{
    __shared__ int slut[1025];
    for (int i = threadIdx.x; i < 1025; i += TPB) slut[i] = lut[i];
    __syncthreads();

    const int tid  = blockIdx.x * TPB + threadIdx.x;
    const int c    = tid & (CC - 1);
    const int b    = tid >> 11;                  // C = 2048 = 2^11
    const int lidx = (b << 21) + c;              // b*T*C + c (loop-invariant VGPR)
    const int w = w_i[c];
    const int u = u_i[c];
    // loop-invariant byte-index constants: idx = 4*delta + 4096
    const int c1  = 4096 - 4 * u;                // output half, e1 side
    const int c1r = 4096 + 4 * u;                // output half, e2 side
    const int c2  = 4096 + 4 * w;                // state half, e1n side
    const int c2r = 4096 - 4 * w;                // state half, e2n side

    int pp = -32768;                             // -(1 << (p_bits-1))
    int aa = 0;
    unsigned bb = 0;

    // lut[clamp(idx4/4, 0, 1024)] on byte-scaled index -> v_med3_i32 + ds_read
    auto eread = [&](int idx4) -> int {
        idx4 = idx4 < 0 ? 0 : (idx4 > 4096 ? 4096 : idx4);
        return *(const int*)((const char*)slut + idx4);
    };

    auto prefetch = [&](int (&kbf)[TB], int (&vbf)[TB], int tbase) {
#pragma unroll
        for (int i = 0; i < TB; ++i) {
            const int* krow = k_i + ((size_t)(unsigned)(tbase + i) << 11); // SGPR base
            const int* vrow = v_i + ((size_t)(unsigned)(tbase + i) << 11);
            kbf[i] = krow[lidx];
            vbf[i] = vrow[lidx];
        }
    };

    auto process = [&](const int (&kbf)[TB], const int (&vbf)[TB], int tbase) {
        int pe1[TB], pe2[TB], pe1n[TB], pe2n[TB];
        // ---- phase A: pp recurrence + all 4*TB LUT reads (deep ds_read pipe)
#pragma unroll
        for (int i = 0; i < TB; ++i) {
            const int kk = kbf[i];
            const int s  = (pp - kk) << 2;       // 4*(pp-kk)
            pe1[i]  = eread(s + c1);             // lut[clamp(1024 + (pp-(k+u)))]
            pe2[i]  = eread(c1r - s);            // lut[clamp(1024 - (pp-(k+u)))]
            pe1n[i] = eread(s + c2);             // lut[clamp(1024 + ((pp+w)-k))]
            pe2n[i] = eread(c2r - s);            // lut[clamp(1024 - ((pp+w)-k))]
            const int ppw = pp + w;
            pp = ppw > kk ? ppw : kk;            // next pp (v_max_i32)
        }
        // ---- phase B: aa/bb updates + RNE division + store
#pragma unroll
        for (int i = 0; i < TB; ++i) {
            const int vv = vbf[i];
            const int e1 = pe1[i], e2 = pe2[i], e1n = pe1n[i], e2n = pe2n[i];
            // output half-step
            const int aa1 = sat_add(rne14_s(aa, e1), vv * e2);
            unsigned bb1 = rne14_u(bb, (unsigned)e1) + (unsigned)e2;
            bb1 = bb1 > 0xFFFFFFu ? 0xFFFFFFu : bb1;       // v_min_u32 (bb_hi)
            // y = div_rne(aa1, max(bb1,1)) — leaf, off the state critical path
            const unsigned dd = bb1 > 1u ? bb1 : 1u;       // v_max_u32
            const int sx = aa1 >> 31;
            const unsigned ua = ((unsigned)aa1 ^ (unsigned)sx) - (unsigned)sx;
            const unsigned uq = ua / dd;
            const unsigned ur = ua - uq * dd;              // mul+sub, no 2nd div
            const unsigned uy = uq + (unsigned)((2u * ur + (uq & 1u)) > dd);
            const int yv = ((int)uy ^ sx) - sx;
            // state half-step
            aa = sat_add(rne14_s(aa1, e1n), vv * e2n);
            unsigned bb2 = rne14_u(bb1, (unsigned)e1n) + (unsigned)e2n;
            bb = bb2 > 0xFFFFFFu ? 0xFFFFFFu : bb2;
            // store: uniform SGPR row base + invariant lane offset
            int* yrow = y + ((size_t)(unsigned)(tbase + i) << 11);
            yrow[lidx] = yv;
        }
    };

    int ka[TB], va[TB], kb2[TB], vb2[TB];
    prefetch(ka, va, 0);
    for (int j = 0; j < NTB2; ++j) {
        const int t0 = 2 * j * TB;
        prefetch(kb2, vb2, t0 + TB);             // block 2j+1 in flight
        process(ka, va, t0);                     // consume block 2j
        if (j + 1 < NTB2) prefetch(ka, va, t0 + 2 * TB);  // block 2j+2 in flight
        process(kb2, vb2, t0 + TB);              // consume block 2j+1
    }
}

extern "C" void kernel_launch(void* const* d_in, const int* in_sizes, int n_in,
                              void* d_out, int out_size, void* d_ws, size_t ws_size,
                              hipStream_t stream) {
    const int* w_i = (const int*)d_in[0];
    const int* u_i = (const int*)d_in[1];
    const int* k_i = (const int*)d_in[2];
    const int* v_i = (const int*)d_in[3];
    const int* lut = (const int*)d_in[4];
    int* y = (int*)d_out;
    dim3 grid(BBATCH * CC / TPB);                // 256 blocks x 64 threads = 16384 lanes
    wkv_int_kernel<<<grid, TPB, 0, stream>>>(w_i, u_i, k_i, v_i, lut, y);
}

// Round 6
// 259.737 us; speedup vs baseline: 1.3173x; 1.3173x over previous
//
#include <hip/hip_runtime.h>
#include <limits.h>

// RWKV integer WKV recurrence on MI355X (gfx950) — 4-wave pipelined version.
//
// Round-5 measurement (absmax=0.0, 217us): VALUBusy 15% (= ~60% of the one
// active SIMD per CU), HBM 7.7% — per-wave issue/serial-chain bound with 3 of
// 4 SIMDs idle. This version splits each channel's step across 4 waves on the
// same CU (grid 256 x 4 waves = 1024 waves = every SIMD on the chip):
//   W0: pp recurrence + med3-clamped LUT reads  -> e-ring      (~12 VALU/step)
//   W1: aa chain (RNE mul-shift + sat-add)      -> aa1-ring    (~15 VALU/step)
//   W2: bb chain (RNE + clip) + dd=max(bb1,1)   -> dd-ring     (~15 VALU/step)
//   W3: y = div_rne(aa1, dd) + store            (pole, ~26 VALU/step)
// Stage math is byte-identical to the verified absmax=0 kernel; values cross
// waves as exact int32 via double-buffered LDS rings, one __syncthreads per
// TB=16-step block (pipeline: W0 on block j, W1/W2 on j-1, W3 on j-2).
// k (W0) and v (W1) are register-prefetched 2 blocks (~1900 cy) ahead.

#define TPB 256
#define CC  2048
#define TT  1024
#define TB  16
#define NTB (TT / TB)      // 64 blocks + 2 drain iterations

static __device__ __forceinline__ int sat_add(int a, int b) {
#if __has_builtin(__builtin_elementwise_add_sat)
    return __builtin_elementwise_add_sat(a, b);   // v_add_i32 ... clamp
#else
    long long s = (long long)a + (long long)b;
    return s < (long long)INT_MIN ? INT_MIN
         : (s > (long long)INT_MAX ? INT_MAX : (int)s);
#endif
}

// RNE((a*e)/2^14), floor form == reference sign-magnitude RNE (verified on HW,
// absmax=0.0 in round 5). Fits int32 for |a| <= 2^31, 0 <= e <= 2^14.
static __device__ __forceinline__ int rne14_s(int a, int e) {
    long long x2 = (long long)a * e + 8192;
    int q1 = (int)((unsigned long long)x2 >> 14);
    int tie = (((unsigned)x2 & 32767u) == 16384u);     // r==8192 && q even
    return q1 - tie;
}

static __device__ __forceinline__ unsigned rne14_u(unsigned a, unsigned e) {
    unsigned long long x2 = (unsigned long long)a * e + 8192u;
    unsigned q1 = (unsigned)(x2 >> 14);
    unsigned tie = (((unsigned)x2 & 32767u) == 16384u);
    return q1 - tie;
}

__launch_bounds__(TPB, 1)
__global__ void wkv_pipe_kernel(const int* __restrict__ w_i, const int* __restrict__ u_i,
                                const int* __restrict__ k_i, const int* __restrict__ v_i,
                                const int* __restrict__ lut, int* __restrict__ y)
{
    __shared__ int      slut[1025];
    __shared__ int      ering[2][TB][4][64];   // e1,e2,e1n,e2n per step per lane (32 KB)
    __shared__ int      aaring[2][TB][64];     // aa1 (8 KB)
    __shared__ unsigned ddring[2][TB][64];     // max(bb1,1) (8 KB)

    for (int i = threadIdx.x; i < 1025; i += TPB) slut[i] = lut[i];
    __syncthreads();

    const int lane = threadIdx.x & 63;
    const int wid  = threadIdx.x >> 6;
    const int bidx = blockIdx.x;                               // 256 blocks, 1/CU
    // chain = bidx*64 + lane; b = chain>>11 and channel-base are wave-uniform
    const size_t ubase = ((size_t)(bidx >> 5) << 21) + (size_t)((bidx & 31) << 6);

    auto eread = [&](int idx4) -> int {        // lut[clamp(idx4/4,0,1024)] via med3
        idx4 = idx4 < 0 ? 0 : (idx4 > 4096 ? 4096 : idx4);
        return *(const int*)((const char*)slut + idx4);
    };

    if (wid == 0) {
        // ---------------- W0: pp recurrence + LUT -> e-ring ----------------
        const int ch = ((bidx & 31) << 6) + lane;
        const int w = w_i[ch], u = u_i[ch];
        const int c1  = 4096 - 4 * u;          // byte-index consts: idx=4*delta+4096
        const int c1r = 4096 + 4 * u;
        const int c2  = 4096 + 4 * w;
        const int c2r = 4096 - 4 * w;
        int pp = -32768;
        int kc[TB], kn[TB];
        const int* kb = k_i + ubase;
#pragma unroll
        for (int i = 0; i < TB; ++i) kc[i] = kb[((size_t)i << 11) + lane];
#pragma unroll
        for (int i = 0; i < TB; ++i) kn[i] = kb[((size_t)(TB + i) << 11) + lane];

        for (int j = 0; j < NTB + 2; ++j) {
            if (j < NTB) {
                const int p = j & 1;
#pragma unroll
                for (int i = 0; i < TB; ++i) {
                    const int kk = kc[i];
                    const int s = (pp - kk) << 2;              // 4*(pp-kk)
                    ering[p][i][0][lane] = eread(s + c1);      // e1 : 1024+(pp-(k+u))
                    ering[p][i][1][lane] = eread(c1r - s);     // e2 : 1024-(pp-(k+u))
                    ering[p][i][2][lane] = eread(s + c2);      // e1n: 1024+((pp+w)-k)
                    ering[p][i][3][lane] = eread(c2r - s);     // e2n: 1024-((pp+w)-k)
                    const int ppw = pp + w;
                    pp = ppw > kk ? ppw : kk;                  // next pp
                }
#pragma unroll
                for (int i = 0; i < TB; ++i) kc[i] = kn[i];
                if (j + 2 < NTB) {
                    const int* kbn = k_i + ubase + ((size_t)((j + 2) * TB) << 11);
#pragma unroll
                    for (int i = 0; i < TB; ++i) kn[i] = kbn[((size_t)i << 11) + lane];
                }
            }
            __syncthreads();
        }
    } else if (wid == 1) {
        // ---------------- W1: aa chain -> aa1-ring ----------------
        int aa = 0;
        int vc[TB], vn[TB];
        const int* vb = v_i + ubase;
#pragma unroll
        for (int i = 0; i < TB; ++i) vc[i] = vb[((size_t)i << 11) + lane];
#pragma unroll
        for (int i = 0; i < TB; ++i) vn[i] = vb[((size_t)(TB + i) << 11) + lane];

        for (int j = 0; j < NTB + 2; ++j) {
            const int jb = j - 1;
            if (jb >= 0 && jb < NTB) {
                const int p = jb & 1;
#pragma unroll
                for (int i = 0; i < TB; ++i) {
                    const int e1  = ering[p][i][0][lane];
                    const int e2  = ering[p][i][1][lane];
                    const int e1n = ering[p][i][2][lane];
                    const int e2n = ering[p][i][3][lane];
                    const int vv = vc[i];
                    const int aa1 = sat_add(rne14_s(aa, e1), vv * e2);
                    aaring[p][i][lane] = aa1;
                    aa = sat_add(rne14_s(aa1, e1n), vv * e2n);
                }
#pragma unroll
                for (int i = 0; i < TB; ++i) vc[i] = vn[i];
                if (jb + 2 < NTB) {
                    const int* vbn = v_i + ubase + ((size_t)((jb + 2) * TB) << 11);
#pragma unroll
                    for (int i = 0; i < TB; ++i) vn[i] = vbn[((size_t)i << 11) + lane];
                }
            }
            __syncthreads();
        }
    } else if (wid == 2) {
        // ---------------- W2: bb chain -> dd-ring ----------------
        unsigned bb = 0;
        for (int j = 0; j < NTB + 2; ++j) {
            const int jb = j - 1;
            if (jb >= 0 && jb < NTB) {
                const int p = jb & 1;
#pragma unroll
                for (int i = 0; i < TB; ++i) {
                    const unsigned e1  = (unsigned)ering[p][i][0][lane];
                    const unsigned e2  = (unsigned)ering[p][i][1][lane];
                    const unsigned e1n = (unsigned)ering[p][i][2][lane];
                    const unsigned e2n = (unsigned)ering[p][i][3][lane];
                    unsigned bb1 = rne14_u(bb, e1) + e2;
                    bb1 = bb1 > 0xFFFFFFu ? 0xFFFFFFu : bb1;   // clip to bb_hi
                    ddring[p][i][lane] = bb1 > 1u ? bb1 : 1u;  // dd = max(bb1,1)
                    unsigned bb2 = rne14_u(bb1, e1n) + e2n;
                    bb = bb2 > 0xFFFFFFu ? 0xFFFFFFu : bb2;
                }
            }
            __syncthreads();
        }
    } else {
        // ---------------- W3: y = div_rne(aa1, dd) + store ----------------
        for (int j = 0; j < NTB + 2; ++j) {
            const int jb = j - 2;
            if (jb >= 0) {                                     // jb <= NTB-1 by loop bound
                const int p = jb & 1;
                int* yb = y + ubase + ((size_t)(jb * TB) << 11);
#pragma unroll
                for (int i = 0; i < TB; ++i) {
                    const int aa1 = aaring[p][i][lane];
                    const unsigned dd = ddring[p][i][lane];
                    const int sx = aa1 >> 31;
                    const unsigned ua = ((unsigned)aa1 ^ (unsigned)sx) - (unsigned)sx;
                    const unsigned uq = ua / dd;               // exact compiler sequence
                    const unsigned ur = ua - uq * dd;
                    const unsigned uy = uq + (unsigned)((2u * ur + (uq & 1u)) > dd);
                    yb[((size_t)i << 11) + lane] = ((int)uy ^ sx) - sx;
                }
            }
            __syncthreads();
        }
    }
}

extern "C" void kernel_launch(void* const* d_in, const int* in_sizes, int n_in,
                              void* d_out, int out_size, void* d_ws, size_t ws_size,
                              hipStream_t stream) {
    const int* w_i = (const int*)d_in[0];
    const int* u_i = (const int*)d_in[1];
    const int* k_i = (const int*)d_in[2];
    const int* v_i = (const int*)d_in[3];
    const int* lut = (const int*)d_in[4];
    int* y = (int*)d_out;
    dim3 grid(8 * CC / 64);                    // 256 blocks x 256 threads (4 waves)
    wkv_pipe_kernel<<<grid, TPB, 0, stream>>>(w_i, u_i, k_i, v_i, lut, y);
}

// Round 8
// 255.409 us; speedup vs baseline: 1.3396x; 1.0169x over previous
//
#include <hip/hip_runtime.h>
#include <limits.h>

// RWKV integer WKV recurrence on MI355X (gfx950) — 4-wave pipeline, round 8
// (resubmission of the unbenched round-7 kernel; broker timed out).
//
// Round-6 (132us, absmax=0): VALUBusy 26% -> each wave stalls ~74% on per-step
// scalar ds_read latency (e-ring strided b32 reads, load->wait->use each step).
// This version keeps the verified math bit-identical and restructures data flow:
//   - ering[2][TB][64][4]: lane-contiguous e-values -> one ds_read_b128 /step,
//     all TB=16 loads issued up-front into VGPRs (one latency, not 16).
//   - W0 phase-split: pp-chain + all 64 LUT reads issue first (reads don't
//     feed the pp chain), then 16x ds_write_b128 as data returns.
//   - yring[2][TB][64][2]: {aa1, dd} as int2 -> single ds_read_b64 in W3.
//   - W3 divide in f64: y = rint((double)aa1/(double)dd). Exact: |aa1| <= 2^31
//     << 2^52, so correctly-rounded IEEE division cannot cross a half-integer
//     boundary (distance >= 1/(2*dd) > |aa1|*2^-53); exact ties m/2 are f64-
//     representable; rint is half-even + odd-symmetric == reference div_rne.
// Waves: W0 pp/LUT -> W1 aa-chain, W2 bb-chain -> W3 divide+store; double-
// buffered rings; one __syncthreads per TB-step block (producer writes parity
// p while consumers read 1-p, swap only across the barrier); fill/drain 2/66.

#define TPB 256
#define CC  2048
#define TT  1024
#define TB  16
#define NTB (TT / TB)      // 64 blocks + 2 drain iterations

static __device__ __forceinline__ int sat_add(int a, int b) {
#if __has_builtin(__builtin_elementwise_add_sat)
    return __builtin_elementwise_add_sat(a, b);   // v_add_i32 ... clamp
#else
    long long s = (long long)a + (long long)b;
    return s < (long long)INT_MIN ? INT_MIN
         : (s > (long long)INT_MAX ? INT_MAX : (int)s);
#endif
}

// RNE((a*e)/2^14), floor form == reference sign-magnitude RNE (HW-verified
// absmax=0 in rounds 5-6). Fits int32 for |a| <= 2^31, 0 <= e <= 2^14.
static __device__ __forceinline__ int rne14_s(int a, int e) {
    long long x2 = (long long)a * e + 8192;
    int q1 = (int)((unsigned long long)x2 >> 14);
    int tie = (((unsigned)x2 & 32767u) == 16384u);     // r==8192 && q even
    return q1 - tie;
}

static __device__ __forceinline__ unsigned rne14_u(unsigned a, unsigned e) {
    unsigned long long x2 = (unsigned long long)a * e + 8192u;
    unsigned q1 = (unsigned)(x2 >> 14);
    unsigned tie = (((unsigned)x2 & 32767u) == 16384u);
    return q1 - tie;
}

__launch_bounds__(TPB, 1)
__global__ void wkv_pipe_kernel(const int* __restrict__ w_i, const int* __restrict__ u_i,
                                const int* __restrict__ k_i, const int* __restrict__ v_i,
                                const int* __restrict__ lut, int* __restrict__ y)
{
    __shared__ int slut[1025];
    __shared__ __align__(16) int ering[2][TB][64][4];  // e1,e2,e1n,e2n contiguous/lane
    __shared__ __align__(16) int yring[2][TB][64][2];  // {aa1, dd} contiguous/lane

    for (int i = threadIdx.x; i < 1025; i += TPB) slut[i] = lut[i];
    __syncthreads();

    const int lane = threadIdx.x & 63;
    const int wid  = threadIdx.x >> 6;
    const int bidx = blockIdx.x;                               // 256 blocks, 1/CU
    const size_t ubase = ((size_t)(bidx >> 5) << 21) + (size_t)((bidx & 31) << 6);

    auto eread = [&](int idx4) -> int {        // lut[clamp(idx4/4,0,1024)] via med3
        idx4 = idx4 < 0 ? 0 : (idx4 > 4096 ? 4096 : idx4);
        return *(const int*)((const char*)slut + idx4);
    };

    if (wid == 0) {
        // -------- W0: pp recurrence + LUT -> ering (reads first, writes after)
        const int ch = ((bidx & 31) << 6) + lane;
        const int w = w_i[ch], u = u_i[ch];
        const int c1  = 4096 - 4 * u;          // byte-index consts: idx=4*delta+4096
        const int c1r = 4096 + 4 * u;
        const int c2  = 4096 + 4 * w;
        const int c2r = 4096 - 4 * w;
        int pp = -32768;
        int kc[TB], kn[TB];
        const int* kb = k_i + ubase;
#pragma unroll
        for (int i = 0; i < TB; ++i) kc[i] = kb[((size_t)i << 11) + lane];
#pragma unroll
        for (int i = 0; i < TB; ++i) kn[i] = kb[((size_t)(TB + i) << 11) + lane];

        for (int j = 0; j < NTB + 2; ++j) {
            if (j < NTB) {
                const int p = j & 1;
                int ea[TB], eb[TB], ec[TB], ed[TB];
                // phase A1: pp chain + issue all 4*TB LUT reads (they don't feed pp)
#pragma unroll
                for (int i = 0; i < TB; ++i) {
                    const int kk = kc[i];
                    const int s = (pp - kk) << 2;              // 4*(pp-kk)
                    ea[i] = eread(s + c1);                     // e1 : 1024+(pp-(k+u))
                    eb[i] = eread(c1r - s);                    // e2 : 1024-(pp-(k+u))
                    ec[i] = eread(s + c2);                     // e1n: 1024+((pp+w)-k)
                    ed[i] = eread(c2r - s);                    // e2n: 1024-((pp+w)-k)
                    const int ppw = pp + w;
                    pp = ppw > kk ? ppw : kk;                  // next pp
                }
                // phase A2: vectorized ring writes
#pragma unroll
                for (int i = 0; i < TB; ++i) {
                    int4 t; t.x = ea[i]; t.y = eb[i]; t.z = ec[i]; t.w = ed[i];
                    *(int4*)&ering[p][i][lane][0] = t;         // ds_write_b128
                }
#pragma unroll
                for (int i = 0; i < TB; ++i) kc[i] = kn[i];
                if (j + 2 < NTB) {
                    const int* kbn = k_i + ubase + ((size_t)((j + 2) * TB) << 11);
#pragma unroll
                    for (int i = 0; i < TB; ++i) kn[i] = kbn[((size_t)i << 11) + lane];
                }
            }
            __syncthreads();
        }
    } else if (wid == 1) {
        // -------- W1: aa chain -> yring[.][.][lane][0]
        int aa = 0;
        int vc[TB], vn[TB];
        const int* vb = v_i + ubase;
#pragma unroll
        for (int i = 0; i < TB; ++i) vc[i] = vb[((size_t)i << 11) + lane];
#pragma unroll
        for (int i = 0; i < TB; ++i) vn[i] = vb[((size_t)(TB + i) << 11) + lane];

        for (int j = 0; j < NTB + 2; ++j) {
            const int jb = j - 1;
            if (jb >= 0 && jb < NTB) {
                const int p = jb & 1;
                int4 ev[TB];
#pragma unroll
                for (int i = 0; i < TB; ++i)                   // all b128 loads upfront
                    ev[i] = *(const int4*)&ering[p][i][lane][0];
#pragma unroll
                for (int i = 0; i < TB; ++i) {
                    const int vv = vc[i];
                    const int aa1 = sat_add(rne14_s(aa, ev[i].x), vv * ev[i].y);
                    yring[p][i][lane][0] = aa1;
                    aa = sat_add(rne14_s(aa1, ev[i].z), vv * ev[i].w);
                }
#pragma unroll
                for (int i = 0; i < TB; ++i) vc[i] = vn[i];
                if (jb + 2 < NTB) {
                    const int* vbn = v_i + ubase + ((size_t)((jb + 2) * TB) << 11);
#pragma unroll
                    for (int i = 0; i < TB; ++i) vn[i] = vbn[((size_t)i << 11) + lane];
                }
            }
            __syncthreads();
        }
    } else if (wid == 2) {
        // -------- W2: bb chain -> yring[.][.][lane][1]
        unsigned bb = 0;
        for (int j = 0; j < NTB + 2; ++j) {
            const int jb = j - 1;
            if (jb >= 0 && jb < NTB) {
                const int p = jb & 1;
                int4 ev[TB];
#pragma unroll
                for (int i = 0; i < TB; ++i)                   // all b128 loads upfront
                    ev[i] = *(const int4*)&ering[p][i][lane][0];
#pragma unroll
                for (int i = 0; i < TB; ++i) {
                    unsigned bb1 = rne14_u(bb, (unsigned)ev[i].x) + (unsigned)ev[i].y;
                    bb1 = bb1 > 0xFFFFFFu ? 0xFFFFFFu : bb1;   // clip to bb_hi
                    yring[p][i][lane][1] = (int)(bb1 > 1u ? bb1 : 1u); // dd=max(bb1,1)
                    unsigned bb2 = rne14_u(bb1, (unsigned)ev[i].z) + (unsigned)ev[i].w;
                    bb = bb2 > 0xFFFFFFu ? 0xFFFFFFu : bb2;
                }
            }
            __syncthreads();
        }
    } else {
        // -------- W3: y = rint(aa1/dd) in f64 (exact == div_rne) + store
        for (int j = 0; j < NTB + 2; ++j) {
            const int jb = j - 2;
            if (jb >= 0) {                                     // jb <= NTB-1 by bound
                const int p = jb & 1;
                int* yb = y + ubase + ((size_t)(jb * TB) << 11);
                int2 t[TB];
#pragma unroll
                for (int i = 0; i < TB; ++i)                   // all b64 loads upfront
                    t[i] = *(const int2*)&yring[p][i][lane][0];
#pragma unroll
                for (int i = 0; i < TB; ++i) {
                    const double qa = (double)t[i].x;          // aa1
                    const double qd = (double)t[i].y;          // dd in [1, 2^24)
                    yb[((size_t)i << 11) + lane] = (int)rint(qa / qd);
                }
            }
            __syncthreads();
        }
    }
}

extern "C" void kernel_launch(void* const* d_in, const int* in_sizes, int n_in,
                              void* d_out, int out_size, void* d_ws, size_t ws_size,
                              hipStream_t stream) {
    const int* w_i = (const int*)d_in[0];
    const int* u_i = (const int*)d_in[1];
    const int* k_i = (const int*)d_in[2];
    const int* v_i = (const int*)d_in[3];
    const int* lut = (const int*)d_in[4];
    int* y = (int*)d_out;
    dim3 grid(8 * CC / 64);                    // 256 blocks x 256 threads (4 waves)
    wkv_pipe_kernel<<<grid, TPB, 0, stream>>>(w_i, u_i, k_i, v_i, lut, y);
}